// Round 4
// baseline (40.522 us; speedup 1.0000x reference)
//
#include <hip/hip_runtime.h>

// Problem constants
#define LIN   4096
#define NCH   8
#define NBS   16
#define NBLK  256           // 16 b  x 16 pb; 1 block/CU
#define THREADS 256
// Per block: 32 grp x 8 consecutive windows = 256 positions; 16 blocks cover pos 0..4095
// of one batch b; pos 4096 (right-pad window) handled as a tail by wave 3 of pb==15.

// d_ws layout (bytes):
//  [0..3]      uint counter (zeroed by hipMemsetAsync each call)
//  [256..]     slots: float slots[NBLK][4] per-block relu'd maxima (always fully written)

// ---------------- register statevector sim (validated R0/R3: absmax 0.0) ----------------
template<int BIT>
__device__ __forceinline__ void apply_rx(float sr[16], float si[16], float c, float s) {
#pragma unroll
  for (int k = 0; k < 16; ++k) {
    if ((k & BIT) == 0) {
      const int a = k, b = k | BIT;
      const float ar = sr[a], ai = si[a], br = sr[b], bi = si[b];
      sr[a] = c * ar + s * bi;
      si[a] = c * ai - s * br;
      sr[b] = c * br + s * ai;
      si[b] = c * bi - s * ar;
    }
  }
}

template<int BIT>
__device__ __forceinline__ void apply_ry(float sr[16], float si[16], float c, float s) {
#pragma unroll
  for (int k = 0; k < 16; ++k) {
    if ((k & BIT) == 0) {
      const int a = k, b = k | BIT;
      const float ar = sr[a], ai = si[a], br = sr[b], bi = si[b];
      sr[a] = c * ar - s * br;
      si[a] = c * ai - s * bi;
      sr[b] = s * ar + c * br;
      si[b] = s * ai + c * bi;
    }
  }
}

template<int CBIT, int TBIT>
__device__ __forceinline__ void apply_cnot(float sr[16], float si[16]) {
#pragma unroll
  for (int k = 0; k < 16; ++k) {
    if ((k & CBIT) != 0 && (k & TBIT) == 0) {
      const int a = k, b = k | TBIT;
      float t;
      t = sr[a]; sr[a] = sr[b]; sr[b] = t;
      t = si[a]; si[a] = si[b]; si[b] = t;
    }
  }
}

__device__ __forceinline__ void basic_layer(float sr[16], float si[16],
                                            const float c[4], const float s[4]) {
  apply_rx<8>(sr, si, c[0], s[0]);
  apply_rx<4>(sr, si, c[1], s[1]);
  apply_rx<2>(sr, si, c[2], s[2]);
  apply_rx<1>(sr, si, c[3], s[3]);
  apply_cnot<8, 4>(sr, si);
  apply_cnot<4, 2>(sr, si);
  apply_cnot<2, 1>(sr, si);
  apply_cnot<1, 8>(sr, si);
}

__device__ void sim_circuit(const float* __restrict__ weights, float w0, float w1, float ev[4]) {
  float wc[3][4], wsn[3][4];
#pragma unroll
  for (int l = 0; l < 3; ++l)
#pragma unroll
    for (int q = 0; q < 4; ++q)
      __sincosf(weights[l * 4 + q] * 0.5f, &wsn[l][q], &wc[l][q]);

  float c0, s0, c1, s1;
  __sincosf(w0 * 0.5f, &s0, &c0);
  __sincosf(w1 * 0.5f, &s1, &c1);

  float sr[16], si[16];
#pragma unroll
  for (int k = 0; k < 16; ++k) { sr[k] = 0.0f; si[k] = 0.0f; }
  sr[0] = 1.0f;

  basic_layer(sr, si, wc[0], wsn[0]);
  apply_ry<8>(sr, si, c0, s0);
  apply_ry<4>(sr, si, c1, s1);
  apply_ry<2>(sr, si, c0, s0);
  apply_ry<1>(sr, si, c1, s1);
  basic_layer(sr, si, wc[1], wsn[1]);
  apply_ry<8>(sr, si, c0, s0);
  apply_ry<4>(sr, si, c1, s1);
  apply_ry<2>(sr, si, c0, s0);
  apply_ry<1>(sr, si, c1, s1);
  basic_layer(sr, si, wc[2], wsn[2]);

  float p[16];
#pragma unroll
  for (int k = 0; k < 16; ++k) p[k] = fmaf(sr[k], sr[k], si[k] * si[k]);

  float a1[8], ev3 = 0.0f;
#pragma unroll
  for (int k = 0; k < 8; ++k) {
    a1[k] = p[2 * k] + p[2 * k + 1];
    ev3 += p[2 * k] - p[2 * k + 1];
  }
  float a2[4], ev2 = 0.0f;
#pragma unroll
  for (int k = 0; k < 4; ++k) {
    a2[k] = a1[2 * k] + a1[2 * k + 1];
    ev2 += a1[2 * k] - a1[2 * k + 1];
  }
  ev[1] = (a2[0] - a2[1]) + (a2[2] - a2[3]);
  ev[0] = (a2[0] + a2[1]) - (a2[2] + a2[3]);
  ev[2] = ev2;
  ev[3] = ev3;
}

// u(w) = [1, cos w, sin w, cos2w, sin2w, cos3w, sin3w, cos4w, sin4w]  (validated R3)
__device__ __forceinline__ void build_u(float w, float u[9]) {
  float c, s;
  __sincosf(w, &s, &c);
  u[0] = 1.0f;
  u[1] = c;            u[2] = s;
  u[3] = fmaf(c, c, -(s * s));
  u[4] = 2.0f * s * c;
  u[5] = fmaf(c, u[3], -(s * u[4]));
  u[6] = fmaf(s, u[3], c * u[4]);
  u[7] = fmaf(c, u[5], -(s * u[6]));
  u[8] = fmaf(s, u[5], c * u[6]);
}

// ---------------- fused kernel ----------------
__global__ __launch_bounds__(THREADS) void fused_kernel(const float* __restrict__ x,
                                                        const float* __restrict__ weights,
                                                        const float* __restrict__ dw,
                                                        const float* __restrict__ db,
                                                        float* __restrict__ out,
                                                        unsigned int* __restrict__ cnt,
                                                        float* __restrict__ slots) {
  __shared__ float E[4][81];
  __shared__ float fb[9][9];
  __shared__ float Csh[432];     // C[q][m][n12], n pad to 12 (48B rows, 16B aligned)
  __shared__ float wvmax[4][4];
  __shared__ float Msh[64];
  __shared__ int flag;

  const int tid = threadIdx.x;
  const int blk = blockIdx.x;
  const int b   = blk >> 4;    // 0..15
  const int pb  = blk & 15;    // 0..15

  // ---- phase 1: per-block redundant fit (validated R3 math) ----
  const float alpha = 6.2831853071795864f / 9.0f;
  if (tid < 81) {
    const int j = tid / 9, k = tid - j * 9;
    float ev[4];
    sim_circuit(weights, alpha * (float)j, alpha * (float)k, ev);
#pragma unroll
    for (int q = 0; q < 4; ++q) E[q][tid] = ev[q];
    const int m = j, jj = k;
    if (m == 0) {
      fb[0][jj] = 1.0f;
    } else {
      const int t = (m + 1) >> 1;
      float sv, cv;
      __sincosf(alpha * (float)(jj * t), &sv, &cv);
      fb[m][jj] = (m & 1) ? cv : sv;
    }
  }
  __syncthreads();
  for (int t = tid; t < 432; t += THREADS) {
    const int q = t / 108, r = t % 108, m = r / 12, n = r % 12;
    float val = 0.0f;
    if (n < 9) {
      float acc = 0.0f;
      for (int j = 0; j < 9; ++j) {
        float inner = 0.0f;
        for (int k = 0; k < 9; ++k) inner = fmaf(fb[n][k], E[q][j * 9 + k], inner);
        acc = fmaf(fb[m][j], inner, acc);
      }
      const float dm = (m == 0) ? 9.0f : 4.5f;
      const float dn = (n == 0) ? 9.0f : 4.5f;
      val = acc / (dm * dn);
    }
    Csh[t] = val;
  }
  __syncthreads();

  // ---- phase 2: 8 consecutive windows per thread ----
  const int ch   = tid & 7;
  const int grp  = tid >> 3;               // 0..31
  const int base = pb * 256 + grp * 8;     // first position handled by this thread
  const float* rowx = x + ((size_t)(b * NCH + ch) << 12);

  float vals[9];
  {
    const int i0 = base - 1;               // max i0+8 = 4095, only low end can underflow
#pragma unroll
    for (int v = 0; v < 9; ++v) {
      const int idx = i0 + v;
      vals[v] = (idx >= 0) ? rowx[idx] : 0.0f;
    }
  }
  float U[9][9];
#pragma unroll
  for (int v = 0; v < 9; ++v) build_u(vals[v], U[v]);

  // window w (pos = base+w): w0 = vals[w] -> U[w], w1 = vals[w+1] -> U[w+1]
  float acc[4][8];
#pragma unroll
  for (int q = 0; q < 4; ++q)
#pragma unroll
    for (int w = 0; w < 8; ++w) acc[q][w] = 0.0f;

#pragma unroll
  for (int q = 0; q < 4; ++q) {
#pragma unroll
    for (int m = 0; m < 9; ++m) {
      const float* rp = Csh + q * 108 + m * 12;
      const float4 a  = *(const float4*)(rp);
      const float4 c4 = *(const float4*)(rp + 4);
      const float  r8 = rp[8];
#pragma unroll
      for (int w = 0; w < 8; ++w) {
        float d = a.x;                         // u1[0] = 1
        d = fmaf(a.y,  U[w + 1][1], d);
        d = fmaf(a.z,  U[w + 1][2], d);
        d = fmaf(a.w,  U[w + 1][3], d);
        d = fmaf(c4.x, U[w + 1][4], d);
        d = fmaf(c4.y, U[w + 1][5], d);
        d = fmaf(c4.z, U[w + 1][6], d);
        d = fmaf(c4.w, U[w + 1][7], d);
        d = fmaf(r8,   U[w + 1][8], d);
        acc[q][w] = fmaf(U[w][m], d, acc[q][w]);
      }
    }
  }

  // channel all-reduce (tid = grp*8 + ch): butterfly over ch bits
#pragma unroll
  for (int mask = 1; mask < 8; mask <<= 1) {
#pragma unroll
    for (int q = 0; q < 4; ++q)
#pragma unroll
      for (int w = 0; w < 8; ++w) acc[q][w] += __shfl_xor(acc[q][w], mask, 64);
  }

  // per-thread max over its 8 positions; relu folded via 0 init
  float mx[4] = {0.0f, 0.0f, 0.0f, 0.0f};
#pragma unroll
  for (int q = 0; q < 4; ++q)
#pragma unroll
    for (int w = 0; w < 8; ++w) mx[q] = fmaxf(mx[q], acc[q][w]);

  // tail: pos 4096, window (x[4095], 0).  u(0) = [1,1,0,1,0,1,0,1,0]
  if (pb == 15 && (tid >> 6) == 3) {       // wave-uniform branch; grp 28..31 in this wave
    float ev9[4];
#pragma unroll
    for (int q = 0; q < 4; ++q) {
      float s = 0.0f;
#pragma unroll
      for (int m = 0; m < 9; ++m) {
        const float* rp = Csh + q * 108 + m * 12;
        const float4 a  = *(const float4*)(rp);
        const float4 c4 = *(const float4*)(rp + 4);
        const float dt = a.x + a.y + a.w + c4.y + c4.w;   // n = 0,1,3,5,7
        s = fmaf(U[8][m], dt, s);
      }
      ev9[q] = (grp == 31) ? s : 0.0f;
    }
#pragma unroll
    for (int mask = 1; mask < 8; mask <<= 1)
#pragma unroll
      for (int q = 0; q < 4; ++q) ev9[q] += __shfl_xor(ev9[q], mask, 64);
#pragma unroll
    for (int q = 0; q < 4; ++q) mx[q] = fmaxf(mx[q], ev9[q]);
  }

  // position-group all-reduce (grp bits 3..5 of lane)
#pragma unroll
  for (int mask = 8; mask < 64; mask <<= 1)
#pragma unroll
    for (int q = 0; q < 4; ++q) mx[q] = fmaxf(mx[q], __shfl_xor(mx[q], mask, 64));

  const int wv = tid >> 6;
  if ((tid & 63) == 0) {
#pragma unroll
    for (int q = 0; q < 4; ++q) wvmax[wv][q] = mx[q];
  }
  __syncthreads();
  if (tid < 4) {
    const float m01 = fmaxf(wvmax[0][tid], wvmax[1][tid]);
    const float m23 = fmaxf(wvmax[2][tid], wvmax[3][tid]);
    slots[blk * 4 + tid] = fmaxf(m01, m23);
  }
  __threadfence();
  __syncthreads();
  if (tid == 0) {
    const unsigned int old = atomicAdd(cnt, 1u);
    flag = (old == NBLK - 1) ? 1 : 0;
  }
  __syncthreads();

  // ---- phase 3: last block reduces slots + dense ----
  if (flag) {
    __threadfence();
    if (tid < 64) {
      const int bb = tid >> 2, q = tid & 3;
      float m = 0.0f;
#pragma unroll
      for (int p = 0; p < 16; ++p) m = fmaxf(m, slots[(bb * 16 + p) * 4 + q]);
      Msh[tid] = m;
    }
    __syncthreads();                        // flag is block-uniform -> legal
    if (tid < NBS * 10) {
      const int bb = tid / 10, f = tid - bb * 10;
      float a2 = db[f];
#pragma unroll
      for (int q = 0; q < 4; ++q) a2 = fmaf(Msh[bb * 4 + q], dw[q * 10 + f], a2);
      out[tid] = a2;
    }
  }
}

extern "C" void kernel_launch(void* const* d_in, const int* in_sizes, int n_in,
                              void* d_out, int out_size, void* d_ws, size_t ws_size,
                              hipStream_t stream) {
  const float* x       = (const float*)d_in[0];  // (16, 8, 4096) f32
  const float* weights = (const float*)d_in[1];  // (3, 4) f32
  const float* dw      = (const float*)d_in[2];  // (4, 10) f32
  const float* db      = (const float*)d_in[3];  // (10,) f32
  float* out = (float*)d_out;                    // (16, 10) f32

  unsigned int* cnt = (unsigned int*)d_ws;
  float* slots = (float*)((char*)d_ws + 256);

  hipMemsetAsync(cnt, 0, sizeof(unsigned int), stream);
  fused_kernel<<<NBLK, THREADS, 0, stream>>>(x, weights, dw, db, out, cnt, slots);
}

// Round 5
// 25.694 us; speedup vs baseline: 1.5771x; 1.5771x over previous
//
#include <hip/hip_runtime.h>

// Problem constants
#define LIN   4096
#define NCH   8
#define NBS   16
#define THREADS 256
#define NBLK  512           // 16 b x 32 pb; 2 blocks/CU
#define W     4             // windows per thread
// Per block: 32 grp x 4 windows = 128 positions; 32 pb cover pos 0..4095 of one b.
// pos 4096 (right-pad window) handled as tail by wave 3 of pb==31 blocks.

// d_ws layout: float slots[NBLK][4] — per-block relu'd maxima, always fully written
// by main before finish reads them (stream order). No init needed, no atomics.

// ---------------- register statevector sim (validated R0/R3/R4: absmax 0.0) ----------------
template<int BIT>
__device__ __forceinline__ void apply_rx(float sr[16], float si[16], float c, float s) {
#pragma unroll
  for (int k = 0; k < 16; ++k) {
    if ((k & BIT) == 0) {
      const int a = k, b = k | BIT;
      const float ar = sr[a], ai = si[a], br = sr[b], bi = si[b];
      sr[a] = c * ar + s * bi;
      si[a] = c * ai - s * br;
      sr[b] = c * br + s * ai;
      si[b] = c * bi - s * ar;
    }
  }
}

template<int BIT>
__device__ __forceinline__ void apply_ry(float sr[16], float si[16], float c, float s) {
#pragma unroll
  for (int k = 0; k < 16; ++k) {
    if ((k & BIT) == 0) {
      const int a = k, b = k | BIT;
      const float ar = sr[a], ai = si[a], br = sr[b], bi = si[b];
      sr[a] = c * ar - s * br;
      si[a] = c * ai - s * bi;
      sr[b] = s * ar + c * br;
      si[b] = s * ai + c * bi;
    }
  }
}

template<int CBIT, int TBIT>
__device__ __forceinline__ void apply_cnot(float sr[16], float si[16]) {
#pragma unroll
  for (int k = 0; k < 16; ++k) {
    if ((k & CBIT) != 0 && (k & TBIT) == 0) {
      const int a = k, b = k | TBIT;
      float t;
      t = sr[a]; sr[a] = sr[b]; sr[b] = t;
      t = si[a]; si[a] = si[b]; si[b] = t;
    }
  }
}

__device__ __forceinline__ void basic_layer(float sr[16], float si[16],
                                            const float c[4], const float s[4]) {
  apply_rx<8>(sr, si, c[0], s[0]);
  apply_rx<4>(sr, si, c[1], s[1]);
  apply_rx<2>(sr, si, c[2], s[2]);
  apply_rx<1>(sr, si, c[3], s[3]);
  apply_cnot<8, 4>(sr, si);
  apply_cnot<4, 2>(sr, si);
  apply_cnot<2, 1>(sr, si);
  apply_cnot<1, 8>(sr, si);
}

__device__ void sim_circuit(const float* __restrict__ weights, float w0, float w1, float ev[4]) {
  float wc[3][4], wsn[3][4];
#pragma unroll
  for (int l = 0; l < 3; ++l)
#pragma unroll
    for (int q = 0; q < 4; ++q)
      __sincosf(weights[l * 4 + q] * 0.5f, &wsn[l][q], &wc[l][q]);

  float c0, s0, c1, s1;
  __sincosf(w0 * 0.5f, &s0, &c0);
  __sincosf(w1 * 0.5f, &s1, &c1);

  float sr[16], si[16];
#pragma unroll
  for (int k = 0; k < 16; ++k) { sr[k] = 0.0f; si[k] = 0.0f; }
  sr[0] = 1.0f;

  basic_layer(sr, si, wc[0], wsn[0]);
  apply_ry<8>(sr, si, c0, s0);
  apply_ry<4>(sr, si, c1, s1);
  apply_ry<2>(sr, si, c0, s0);
  apply_ry<1>(sr, si, c1, s1);
  basic_layer(sr, si, wc[1], wsn[1]);
  apply_ry<8>(sr, si, c0, s0);
  apply_ry<4>(sr, si, c1, s1);
  apply_ry<2>(sr, si, c0, s0);
  apply_ry<1>(sr, si, c1, s1);
  basic_layer(sr, si, wc[2], wsn[2]);

  float p[16];
#pragma unroll
  for (int k = 0; k < 16; ++k) p[k] = fmaf(sr[k], sr[k], si[k] * si[k]);

  float a1[8], ev3 = 0.0f;
#pragma unroll
  for (int k = 0; k < 8; ++k) {
    a1[k] = p[2 * k] + p[2 * k + 1];
    ev3 += p[2 * k] - p[2 * k + 1];
  }
  float a2[4], ev2 = 0.0f;
#pragma unroll
  for (int k = 0; k < 4; ++k) {
    a2[k] = a1[2 * k] + a1[2 * k + 1];
    ev2 += a1[2 * k] - a1[2 * k + 1];
  }
  ev[1] = (a2[0] - a2[1]) + (a2[2] - a2[3]);
  ev[0] = (a2[0] + a2[1]) - (a2[2] + a2[3]);
  ev[2] = ev2;
  ev[3] = ev3;
}

// u(w) = [1, cos w, sin w, cos2w, sin2w, cos3w, sin3w, cos4w, sin4w]  (validated R3)
__device__ __forceinline__ void build_u(float w, float u[9]) {
  float c, s;
  __sincosf(w, &s, &c);
  u[0] = 1.0f;
  u[1] = c;            u[2] = s;
  u[3] = fmaf(c, c, -(s * s));
  u[4] = 2.0f * s * c;
  u[5] = fmaf(c, u[3], -(s * u[4]));
  u[6] = fmaf(s, u[3], c * u[4]);
  u[7] = fmaf(c, u[5], -(s * u[6]));
  u[8] = fmaf(s, u[5], c * u[6]);
}

// ---------------- main: redundant per-block fit + 4 windows/thread ----------------
__global__ __launch_bounds__(THREADS) void fused_main(const float* __restrict__ x,
                                                      const float* __restrict__ weights,
                                                      float* __restrict__ slots) {
  __shared__ float E[4][81];
  __shared__ float fb[9][9];
  __shared__ float T[4][81];     // T[q][j*9+n] = sum_k fb[n][k] E[q][j*9+k]
  __shared__ float Csh[432];     // C[q][m][n12], n padded to 12
  __shared__ float wvmax[4][4];

  const int tid = threadIdx.x;
  const int blk = blockIdx.x;
  const int b   = blk >> 5;    // 0..15
  const int pb  = blk & 31;    // 0..31
  const int ch   = tid & 7;
  const int grp  = tid >> 3;               // 0..31
  const int base = pb * 128 + grp * 4;     // first position of this thread

  // early x loads (prefetch under phase 1)
  const float* rowx = x + ((size_t)(b * NCH + ch) << 12);
  float vals[W + 1];
  {
    const int i0 = base - 1;               // only low edge can underflow; max base+3 = 4095
#pragma unroll
    for (int v = 0; v < W + 1; ++v) {
      const int idx = i0 + v;
      vals[v] = (idx >= 0) ? rowx[idx] : 0.0f;
    }
  }
  float U[W + 1][9];
#pragma unroll
  for (int v = 0; v < W + 1; ++v) build_u(vals[v], U[v]);

  // ---- phase 1: per-block fit (two-stage projection) ----
  const float alpha = 6.2831853071795864f / 9.0f;
  if (tid < 81) {
    const int j = tid / 9, k = tid - j * 9;
    float ev[4];
    sim_circuit(weights, alpha * (float)j, alpha * (float)k, ev);
#pragma unroll
    for (int q = 0; q < 4; ++q) E[q][tid] = ev[q];
    const int m = j, jj = k;
    if (m == 0) {
      fb[0][jj] = 1.0f;
    } else {
      const int t = (m + 1) >> 1;
      float sv, cv;
      __sincosf(alpha * (float)(jj * t), &sv, &cv);
      fb[m][jj] = (m & 1) ? cv : sv;
    }
  }
  __syncthreads();
  // stage A: T[q][j][n]
  for (int t = tid; t < 324; t += THREADS) {
    const int q = t / 81, r = t - q * 81, j = r / 9, n = r - j * 9;
    float acc = 0.0f;
#pragma unroll
    for (int k = 0; k < 9; ++k) acc = fmaf(fb[n][k], E[q][j * 9 + k], acc);
    T[q][j * 9 + n] = acc;
  }
  __syncthreads();
  // stage B: C[q][m][n] = (sum_j fb[m][j] T[q][j][n]) / (dm dn)
  for (int t = tid; t < 432; t += THREADS) {
    const int q = t / 108, r = t - q * 108, m = r / 12, n = r - m * 12;
    float val = 0.0f;
    if (n < 9) {
      float acc = 0.0f;
#pragma unroll
      for (int j = 0; j < 9; ++j) acc = fmaf(fb[m][j], T[q][j * 9 + n], acc);
      const float dm = (m == 0) ? 9.0f : 4.5f;
      const float dn = (n == 0) ? 9.0f : 4.5f;
      val = acc / (dm * dn);
    }
    Csh[t] = val;
  }
  __syncthreads();

  // ---- phase 2: 4 windows/thread, ev = u(w0)^T C u(w1) ----
  float acc[4][W];
#pragma unroll
  for (int q = 0; q < 4; ++q)
#pragma unroll
    for (int w = 0; w < W; ++w) acc[q][w] = 0.0f;

#pragma unroll
  for (int q = 0; q < 4; ++q) {
#pragma unroll
    for (int m = 0; m < 9; ++m) {
      const float* rp = Csh + q * 108 + m * 12;
      const float4 A  = *(const float4*)(rp);
      const float4 Bv = *(const float4*)(rp + 4);
      const float  r8 = rp[8];
#pragma unroll
      for (int w = 0; w < W; ++w) {
        float d = A.x;                         // u1[0] = 1
        d = fmaf(A.y,  U[w + 1][1], d);
        d = fmaf(A.z,  U[w + 1][2], d);
        d = fmaf(A.w,  U[w + 1][3], d);
        d = fmaf(Bv.x, U[w + 1][4], d);
        d = fmaf(Bv.y, U[w + 1][5], d);
        d = fmaf(Bv.z, U[w + 1][6], d);
        d = fmaf(Bv.w, U[w + 1][7], d);
        d = fmaf(r8,   U[w + 1][8], d);
        acc[q][w] = fmaf(U[w][m], d, acc[q][w]);
      }
    }
  }

  // channel all-reduce (tid = grp*8 + ch)
#pragma unroll
  for (int mask = 1; mask < 8; mask <<= 1)
#pragma unroll
    for (int q = 0; q < 4; ++q)
#pragma unroll
      for (int w = 0; w < W; ++w) acc[q][w] += __shfl_xor(acc[q][w], mask, 64);

  // per-thread max over its windows; relu folded via 0 init
  float mx[4] = {0.0f, 0.0f, 0.0f, 0.0f};
#pragma unroll
  for (int q = 0; q < 4; ++q)
#pragma unroll
    for (int w = 0; w < W; ++w) mx[q] = fmaxf(mx[q], acc[q][w]);

  // tail: pos 4096, window (x[4095], 0); u(0) = [1,1,0,1,0,1,0,1,0]
  if (pb == 31 && (tid >> 6) == 3) {       // wave-uniform; grp 24..31 in this wave
    float ev9[4];
#pragma unroll
    for (int q = 0; q < 4; ++q) {
      float s = 0.0f;
#pragma unroll
      for (int m = 0; m < 9; ++m) {
        const float* rp = Csh + q * 108 + m * 12;
        const float4 A  = *(const float4*)(rp);
        const float4 Bv = *(const float4*)(rp + 4);
        const float dt = A.x + A.y + A.w + Bv.y + Bv.w;   // n = 0,1,3,5,7
        s = fmaf(U[W][m], dt, s);
      }
      ev9[q] = (grp == 31) ? s : 0.0f;     // grp 31 holds x[4095] in vals[4]
    }
#pragma unroll
    for (int mask = 1; mask < 8; mask <<= 1)
#pragma unroll
      for (int q = 0; q < 4; ++q) ev9[q] += __shfl_xor(ev9[q], mask, 64);
#pragma unroll
    for (int q = 0; q < 4; ++q) mx[q] = fmaxf(mx[q], ev9[q]);
  }

  // position-group all-reduce within wave (grp bits)
#pragma unroll
  for (int mask = 8; mask < 64; mask <<= 1)
#pragma unroll
    for (int q = 0; q < 4; ++q) mx[q] = fmaxf(mx[q], __shfl_xor(mx[q], mask, 64));

  const int wv = tid >> 6;
  if ((tid & 63) == 0) {
#pragma unroll
    for (int q = 0; q < 4; ++q) wvmax[wv][q] = mx[q];
  }
  __syncthreads();
  if (tid < 4) {
    const float m01 = fmaxf(wvmax[0][tid], wvmax[1][tid]);
    const float m23 = fmaxf(wvmax[2][tid], wvmax[3][tid]);
    slots[blk * 4 + tid] = fmaxf(m01, m23);
  }
}

// ---------------- finish: reduce slots + dense ----------------
__global__ __launch_bounds__(THREADS) void finish_kernel(const float* __restrict__ slots,
                                                         const float* __restrict__ dw,
                                                         const float* __restrict__ db,
                                                         float* __restrict__ out) {
  __shared__ float Msh[64];
  const int tid = threadIdx.x;
  if (tid < 64) {
    const int bb = tid >> 2, q = tid & 3;
    float m = 0.0f;
#pragma unroll
    for (int p = 0; p < 32; ++p) m = fmaxf(m, slots[((bb << 5) + p) * 4 + q]);
    Msh[tid] = m;
  }
  __syncthreads();
  if (tid < NBS * 10) {
    const int bb = tid / 10, f = tid - bb * 10;
    float a2 = db[f];
#pragma unroll
    for (int q = 0; q < 4; ++q) a2 = fmaf(Msh[bb * 4 + q], dw[q * 10 + f], a2);
    out[tid] = a2;
  }
}

extern "C" void kernel_launch(void* const* d_in, const int* in_sizes, int n_in,
                              void* d_out, int out_size, void* d_ws, size_t ws_size,
                              hipStream_t stream) {
  const float* x       = (const float*)d_in[0];  // (16, 8, 4096) f32
  const float* weights = (const float*)d_in[1];  // (3, 4) f32
  const float* dw      = (const float*)d_in[2];  // (4, 10) f32
  const float* db      = (const float*)d_in[3];  // (10,) f32
  float* out   = (float*)d_out;                  // (16, 10) f32
  float* slots = (float*)d_ws;                   // [NBLK][4]

  fused_main<<<NBLK, THREADS, 0, stream>>>(x, weights, slots);
  finish_kernel<<<1, THREADS, 0, stream>>>(slots, dw, db, out);
}